// Round 15
// baseline (220.819 us; speedup 1.0000x reference)
//
#include <hip/hip_runtime.h>

// CharGRU2: 2-layer GRU (reset_after=true) + dense + softmax, fp32.
// B=2048, T=128, V=256, H=20, L=15.
//
// Round 15 = R11 EXACT (best: 57.4us dispatch; cross-layer pipeline
// L0(t=i)+L1(t=i-1), row-local DPP gate hops, LDS h-staging with wave-uniform
// ds_read_b128 broadcasts, pk_fma dots, 2 waves/SIMD) + ONE change:
//
//   WAVE DE-PHASING. R11's wall is 1076 cyc/SIMD-step with only 656 issued
//   (VALUBusy 61%): ~420 cyc/step NEITHER wave issues, yet the per-wave
//   loop-carried chain is only ~240 cyc -> the two co-resident waves (wave w
//   of block 2k and 2k+1) run bit-identical code and PHASE-LOCK, stalling on
//   the same lgkmcnt/dependency windows simultaneously. Odd blocks now run a
//   ~150-cycle dependent-FMA preamble (volatile asm, wave-uniform branch,
//   result unused) to slide their stall windows into the partner's issue
//   windows.
//
// Evidence trail: R13 (no LDS, readlane) and R14 (1 wave/SIMD, 2 batches)
// both regressed -> broadcast LDS reads are cheap and wave-level TLP is
// irreplaceable; the only unaddressed loss mechanism in the R11 trunk is
// stall-window alignment.

#define BB 2048
#define TT 128
#define HH 20
#define LL 15
#define H3 60

typedef float v2f __attribute__((ext_vector_type(2)));

__device__ __forceinline__ float bclane(float v, int k) {
    return __int_as_float(__builtin_amdgcn_readlane(__float_as_int(v), k));
}
__device__ __forceinline__ float dpp_rshr1(float v) {
    // v_mov_b32_dpp row_shr:1 — lane i <- lane i-1 within its 16-lane row
    return __int_as_float(__builtin_amdgcn_update_dpp(
        0, __float_as_int(v), 0x111, 0xF, 0xF, true));
}
__device__ __forceinline__ float fast_rcp(float x) { return __builtin_amdgcn_rcpf(x); }
__device__ __forceinline__ float sigm(float x) { return fast_rcp(1.f + __expf(-x)); }
__device__ __forceinline__ float tanh_f(float x) { return 1.f - 2.f * fast_rcp(1.f + __expf(2.f * x)); }
#define PIN(v) asm volatile("" : "+v"(v))
#define LDSFENCE() asm volatile("" ::: "memory")

extern "C" __global__ __launch_bounds__(256)
__attribute__((amdgpu_waves_per_eu(2, 2)))
void gru2_kernel(const int* __restrict__ x, const float* __restrict__ W0,
                 const float* __restrict__ U0, const float* __restrict__ b0i,
                 const float* __restrict__ b0r, const float* __restrict__ W1,
                 const float* __restrict__ U1, const float* __restrict__ b1i,
                 const float* __restrict__ b1r, const float* __restrict__ Wd,
                 const float* __restrict__ bd, float* __restrict__ out)
{
    const int lane = threadIdx.x & 63;
    const int w = threadIdx.x >> 6;
    const int b = blockIdx.x * 4 + w;                    // batch = wave id
    const int row = lane >> 4;                           // DPP row 0..3
    const int pos = lane & 15;                           // pos in row
    const int pc  = (pos < 15) ? pos : 14;               // lane 16r+15 dups pos 14
    const int u   = pc / 3;                              // unit-in-row 0..4
    const int p3  = pc % 3;                              // 0:z 1:r 2:h~
    const int j   = row * 5 + u;                         // unit 0..19
    const bool home = (pos < 15) && (p3 == 2);           // 20 h-home lanes
    const int col = p3 * 20 + j;                         // owned gate column

    // ---- WAVE DE-PHASING: odd blocks burn ~150 dependent cycles ----
    float junk = (float)lane;
    if (blockIdx.x & 1) {
#pragma unroll
        for (int k = 0; k < 30; ++k)
            asm volatile("v_fma_f32 %0, %0, 1.0, 0.5" : "+v"(junk));
    }
    PIN(junk);                                           // keep it live, unused

    // per-wave LDS staging of h0/h1 (wave-uniform broadcast reads)
    __shared__ __align__(16) float hbuf[4][2][24];
    float* h0buf = &hbuf[w][0][0];
    float* h1buf = &hbuf[w][1][0];
    if (home) { h0buf[j] = 0.f; h1buf[j] = 0.f; }
    LDSFENCE();

    // ---- weight columns (k-pair packed) into VGPRs, pinned ----
    v2f u0p[10], w1p[10], u1p[10];
#pragma unroll
    for (int q = 0; q < 10; ++q) {
        const int k0 = (2 * q) * H3, k1 = (2 * q + 1) * H3;
        u0p[q] = v2f{U0[k0 + col], U0[k1 + col]};
        w1p[q] = v2f{W1[k0 + col], W1[k1 + col]};
        u1p[q] = v2f{U1[k0 + col], U1[k1 + col]};
    }
#pragma unroll
    for (int q = 0; q < 10; ++q) { PIN(u0p[q]); PIN(w1p[q]); PIN(u1p[q]); }
    float bi0 = b0i[col], br0 = b0r[col], bi1 = b1i[col], br1 = b1r[col];
    PIN(bi0); PIN(br0); PIN(bi1); PIN(br1);

    // ---- tokens ----
    const int* xrow = x + b * TT;
    const int tokA = xrow[lane];
    const int tokB = xrow[64 + lane];

    float h0 = 0.f, h1 = 0.f;                            // home lanes hold state

    // ---- W0 pipeline: row t ready, row t+1 raw, token t+2 staged ----
    const int tok0 = __builtin_amdgcn_readlane(tokA, 0);
    const int tok1 = __builtin_amdgcn_readlane(tokA, 1);
    int tokn2 = __builtin_amdgcn_readlane(tokA, 2);
    float xw_cur = W0[tok0 * H3 + col] + bi0;
    float xw_nxt = W0[tok1 * H3 + col];

    // ---- prologue: L0 for t=0 (h0_{-1}=0 -> rec0 = br0) ----
    {
        const float pf = W0[tokn2 * H3 + col];
        const int tokn3 = __builtin_amdgcn_readlane(tokA, 3);
        const float rec0 = br0;
        const float sg0 = sigm(xw_cur + rec0);           // z on p=0, r on p=1
        const float rv0 = dpp_rshr1(sg0);                // home <- r_j
        const float zv0 = dpp_rshr1(rv0);                // home <- z_j
        const float hh0 = tanh_f(xw_cur + rv0 * rec0);
        h0 = fmaf(zv0, h0 - hh0, hh0);
        if (home) h0buf[j] = h0;
        LDSFENCE();
        xw_cur = xw_nxt + bi0; xw_nxt = pf; tokn2 = tokn3;
    }

    // ---- main loop: i = 1..127, L0(t=i) + L1(t=i-1) ----
#pragma unroll 2
    for (int i = 1; i < TT; ++i) {
        const int t3 = (i + 3 < TT) ? (i + 3) : (TT - 1);
        const float pf = W0[tokn2 * H3 + col];
        const int tokn3 = __builtin_amdgcn_readlane(t3 < 64 ? tokA : tokB, t3 & 63);

        // broadcast reads: h0buf = h0_{i-1}, h1buf = h1_{i-2}
        const float4* h0q = (const float4*)h0buf;
        const float4* h1q = (const float4*)h1buf;
        v2f a0 = v2f{br0, 0.f};   // rec0 (L0 t=i)
        v2f a1 = v2f{bi1, 0.f};   // xw1  (L1 t=i-1)
        v2f a2 = v2f{br1, 0.f};   // rec1 (L1 t=i-1)
#pragma unroll
        for (int q = 0; q < 5; ++q) {
            const float4 hv0 = h0q[q];
            const float4 hv1 = h1q[q];
            const v2f hA = v2f{hv0.x, hv0.y}, hB = v2f{hv0.z, hv0.w};
            const v2f gA = v2f{hv1.x, hv1.y}, gB = v2f{hv1.z, hv1.w};
            a0 = __builtin_elementwise_fma(hA, u0p[2 * q], a0);
            a0 = __builtin_elementwise_fma(hB, u0p[2 * q + 1], a0);
            a1 = __builtin_elementwise_fma(hA, w1p[2 * q], a1);
            a1 = __builtin_elementwise_fma(hB, w1p[2 * q + 1], a1);
            a2 = __builtin_elementwise_fma(gA, u1p[2 * q], a2);
            a2 = __builtin_elementwise_fma(gB, u1p[2 * q + 1], a2);
        }
        const float rec0 = a0.x + a0.y;
        const float xw1  = a1.x + a1.y;
        const float rec1 = a2.x + a2.y;

        // ---- L0 gates (t=i): row-local DPP hops ----
        const float sg0 = sigm(xw_cur + rec0);
        const float rv0 = dpp_rshr1(sg0);
        const float zv0 = dpp_rshr1(rv0);
        const float hh0 = tanh_f(xw_cur + rv0 * rec0);
        h0 = fmaf(zv0, h0 - hh0, hh0);
        if (home) h0buf[j] = h0;                         // for next iter
        LDSFENCE();

        // ---- L1 gates (t=i-1): independent of L0 above ----
        const float sg1 = sigm(xw1 + rec1);
        const float rv1 = dpp_rshr1(sg1);
        const float zv1 = dpp_rshr1(rv1);
        const float hh1 = tanh_f(xw1 + rv1 * rec1);
        h1 = fmaf(zv1, h1 - hh1, hh1);
        if (home) h1buf[j] = h1;                         // for next iter
        LDSFENCE();

        // rotate W0 pipeline
        xw_cur = xw_nxt + bi0; xw_nxt = pf; tokn2 = tokn3;
    }

    // ---- epilogue: L1 for t=127 (h0buf = h0_127, h1buf = h1_126) ----
    {
        const float4* h0q = (const float4*)h0buf;
        const float4* h1q = (const float4*)h1buf;
        v2f a1 = v2f{bi1, 0.f}, a2 = v2f{br1, 0.f};
#pragma unroll
        for (int q = 0; q < 5; ++q) {
            const float4 hv0 = h0q[q];
            const float4 hv1 = h1q[q];
            a1 = __builtin_elementwise_fma(v2f{hv0.x, hv0.y}, w1p[2 * q], a1);
            a1 = __builtin_elementwise_fma(v2f{hv0.z, hv0.w}, w1p[2 * q + 1], a1);
            a2 = __builtin_elementwise_fma(v2f{hv1.x, hv1.y}, u1p[2 * q], a2);
            a2 = __builtin_elementwise_fma(v2f{hv1.z, hv1.w}, u1p[2 * q + 1], a2);
        }
        const float xw1 = a1.x + a1.y, rec1 = a2.x + a2.y;
        const float sg1 = sigm(xw1 + rec1);
        const float rv1 = dpp_rshr1(sg1);
        const float zv1 = dpp_rshr1(rv1);
        const float hh1 = tanh_f(xw1 + rv1 * rec1);
        h1 = fmaf(zv1, h1 - hh1, hh1);
        if (home) h1buf[j] = h1;                         // final h1
        LDSFENCE();
    }

    // ---- dense (h1 @ Wd + bd) + softmax, lanes 0..14 ----
    const int l = lane < LL ? lane : LL - 1;
    float acc = bd[l];
#pragma unroll
    for (int k = 0; k < HH; ++k)
        acc = fmaf(h1buf[k], Wd[k * LL + l], acc);       // LDS broadcast reads

    float m = acc;
#pragma unroll
    for (int i = 0; i < LL; ++i) m = fmaxf(m, bclane(acc, i));
    const float e = __expf(acc - m);
    float s = 0.f;
#pragma unroll
    for (int i = 0; i < LL; ++i) s += bclane(e, i);
    const float pr = e * fast_rcp(s);

    if (lane < LL) out[b * LL + lane] = pr;
}

extern "C" void kernel_launch(void* const* d_in, const int* in_sizes, int n_in,
                              void* d_out, int out_size, void* d_ws, size_t ws_size,
                              hipStream_t stream) {
    const int*   x   = (const int*)  d_in[0];
    const float* W0  = (const float*)d_in[1];
    const float* U0  = (const float*)d_in[2];
    const float* b0i = (const float*)d_in[3];
    const float* b0r = (const float*)d_in[4];
    const float* W1  = (const float*)d_in[5];
    const float* U1  = (const float*)d_in[6];
    const float* b1i = (const float*)d_in[7];
    const float* b1r = (const float*)d_in[8];
    const float* Wd  = (const float*)d_in[9];
    const float* bd  = (const float*)d_in[10];
    // d_in[11] = drop_rate (identity), unused
    float* out = (float*)d_out;

    // 1 batch/wave, 4 waves/block -> 512 blocks = 2 blocks/CU = 2 waves/SIMD.
    dim3 grid(BB / 4), block(256);
    hipLaunchKernelGGL(gru2_kernel, grid, block, 0, stream,
                       x, W0, U0, b0i, b0r, W1, U1, b1i, b1r, Wd, bd, out);
}

// Round 16
// 140.767 us; speedup vs baseline: 1.5687x; 1.5687x over previous
//
#include <hip/hip_runtime.h>

// CharGRU2: 2-layer GRU (reset_after=true) + dense + softmax, fp32.
// B=2048, T=128, V=256, H=20, L=15.
//
// Round 16: LAYER-SPLIT WAVE SPECIALIZATION on the R11 trunk.
//
// Ledger: R11/R12 = 57.4us (best). R13 (no-LDS readlane), R14 (2 batches/
// wave @ 1 wave/SIMD), R15 (phase-skew) all regressed. R11's config is
// TLP-maximal for batch parallelism (2048x60 lane-slots ~= the 2-wave/SIMD
// capacity), yet ~420 cyc/SIMD-step neither wave issues. More TLP can only
// come from splitting WORK: wave pairs specialize — an L0 wave runs layer 0
// for its batch, a partner L1 wave runs layer 1 one step behind, h0 handed
// through a double-buffered LDS slot, one __syncthreads per step.
// -> 4096 waves = 4 waves/SIMD (2x stall coverage), per-SIMD issue ~same
// (8-wave blocks: SIMD s hosts wave s (L0) + wave s+4 (L1) per block).
// Per-role VGPRs ~110 < 128-reg budget at 4 waves/EU (waves_per_eu(4,4)).
//
// Layout per batch unchanged from R11: lane 16r+3u+p owns gate column
// p*20+(5r+u) (p=0:z 1:r 2:h~); gate hops = 2 chained v_mov_dpp row_shr:1;
// h replicated via wave-uniform ds_read_b128 broadcasts (R13 proved cheap).
//
// Schedule (iter i = 0..128, all waves run all iters + barrier):
//   L0 wave (i<128):  rec0 = h0(t=i-1)@U0  [slot (i-1)&1] -> gates ->
//                     h0(t=i) -> write slot i&1 ; W0 pipeline rotate.
//   L1 wave (i>=1):   xw1 = h0(t=i-1)@W1 [slot (i-1)&1], rec1 = h1@U1
//                     [private h1s] -> gates -> h1(t=i-1) -> write h1s.
//   __syncthreads().
// Double-buffer parity: writer slot i&1 never collides with reader slot
// (i-1)&1; reuse is 2 steps later, sequenced by the barriers.

#define BB 2048
#define TT 128
#define HH 20
#define LL 15
#define H3 60

typedef float v2f __attribute__((ext_vector_type(2)));

__device__ __forceinline__ float bclane(float v, int k) {
    return __int_as_float(__builtin_amdgcn_readlane(__float_as_int(v), k));
}
__device__ __forceinline__ float dpp_rshr1(float v) {
    return __int_as_float(__builtin_amdgcn_update_dpp(
        0, __float_as_int(v), 0x111, 0xF, 0xF, true));
}
__device__ __forceinline__ float fast_rcp(float x) { return __builtin_amdgcn_rcpf(x); }
__device__ __forceinline__ float sigm(float x) { return fast_rcp(1.f + __expf(-x)); }
__device__ __forceinline__ float tanh_f(float x) { return 1.f - 2.f * fast_rcp(1.f + __expf(2.f * x)); }
#define PIN(v) asm volatile("" : "+v"(v))
#define LDSFENCE() asm volatile("" ::: "memory")

extern "C" __global__ __launch_bounds__(512)
__attribute__((amdgpu_waves_per_eu(4, 4)))
void gru2_kernel(const int* __restrict__ x, const float* __restrict__ W0,
                 const float* __restrict__ U0, const float* __restrict__ b0i,
                 const float* __restrict__ b0r, const float* __restrict__ W1,
                 const float* __restrict__ U1, const float* __restrict__ b1i,
                 const float* __restrict__ b1r, const float* __restrict__ Wd,
                 const float* __restrict__ bd, float* __restrict__ out)
{
    const int lane = threadIdx.x & 63;
    const int wv = threadIdx.x >> 6;                     // 0..7
    const bool isL1 = (wv >= 4);                         // wave role
    const int wb = wv & 3;                               // batch in block
    const int b = blockIdx.x * 4 + wb;

    const int pos = lane & 15;
    const int pc  = (pos < 15) ? pos : 14;               // lane 16r+15 dups
    const int u   = pc / 3;
    const int p3  = pc % 3;                              // 0:z 1:r 2:h~
    const int j   = (lane >> 4) * 5 + u;                 // unit 0..19
    const bool home = (pos < 15) && (p3 == 2);
    const int col = p3 * 20 + j;

    // h0 hand-off (double-buffered) + L1-private h1 staging
    __shared__ __align__(16) float h0x[4][2][24];
    __shared__ __align__(16) float h1s[4][24];
    if (home) { h0x[wb][0][j] = 0.f; h0x[wb][1][j] = 0.f; h1s[wb][j] = 0.f; }
    __syncthreads();

    // ---- role-specific weight columns (k-pair packed), pinned ----
    // L0: wA = U0 (rec0).  L1: wA = W1 (xw1), wB = U1 (rec1).
    const float* MA = isL1 ? W1 : U0;
    const float* MB = isL1 ? U1 : U0;                    // L0: dead path
    v2f wA[10], wB[10];
#pragma unroll
    for (int q = 0; q < 10; ++q) {
        const int k0 = (2 * q) * H3, k1 = (2 * q + 1) * H3;
        wA[q] = v2f{MA[k0 + col], MA[k1 + col]};
        wB[q] = v2f{MB[k0 + col], MB[k1 + col]};
    }
#pragma unroll
    for (int q = 0; q < 10; ++q) { PIN(wA[q]); PIN(wB[q]); }
    const float dbA = isL1 ? b1i[col] : b0r[col];        // dotA bias
    const float dbB = isL1 ? b1r[col] : 0.f;             // dotB bias (L1 only)
    const float bi0c = b0i[col];                         // L0 xw pipeline

    // ---- L0-only: token + W0 software pipeline ----
    const int* xrow = x + b * TT;
    int tokA = 0, tokB = 0, tokn2 = 0;
    float xw_cur = 0.f, xw_nxt = 0.f;
    if (!isL1) {
        tokA = xrow[lane];
        tokB = xrow[64 + lane];
        const int tok0 = __builtin_amdgcn_readlane(tokA, 0);
        const int tok1 = __builtin_amdgcn_readlane(tokA, 1);
        tokn2 = __builtin_amdgcn_readlane(tokA, 2);
        xw_cur = W0[tok0 * H3 + col] + bi0c;
        xw_nxt = W0[tok1 * H3 + col];
    }

    float h0 = 0.f, h1 = 0.f;

    for (int i = 0; i <= TT; ++i) {
        if (!isL1) {
            if (i < TT) {
                // prefetch W0 row for t+2, token for t+3
                const int t3 = (i + 3 < TT) ? (i + 3) : (TT - 1);
                const float pf = W0[tokn2 * H3 + col];
                const int tokn3 =
                    __builtin_amdgcn_readlane(t3 < 64 ? tokA : tokB, t3 & 63);

                // rec0 = h0(t=i-1) @ U0 + br0  (slot (i-1)&1, broadcast reads)
                const float4* hq = (const float4*)&h0x[wb][(i + 1) & 1][0];
                v2f a0 = v2f{dbA, 0.f};
#pragma unroll
                for (int q = 0; q < 5; ++q) {
                    const float4 hv = hq[q];
                    a0 = __builtin_elementwise_fma(v2f{hv.x, hv.y}, wA[2 * q], a0);
                    a0 = __builtin_elementwise_fma(v2f{hv.z, hv.w}, wA[2 * q + 1], a0);
                }
                const float rec0 = a0.x + a0.y;

                const float sg0 = sigm(xw_cur + rec0);
                const float rv0 = dpp_rshr1(sg0);
                const float zv0 = dpp_rshr1(rv0);
                const float hh0 = tanh_f(xw_cur + rv0 * rec0);
                h0 = fmaf(zv0, h0 - hh0, hh0);
                if (home) h0x[wb][i & 1][j] = h0;        // hand-off slot i&1
                LDSFENCE();

                xw_cur = xw_nxt + bi0c; xw_nxt = pf; tokn2 = tokn3;
            }
        } else {
            if (i >= 1) {
                // xw1 = h0(t=i-1) @ W1 + bi1 ; rec1 = h1(t=i-2) @ U1 + br1
                const float4* hq = (const float4*)&h0x[wb][(i + 1) & 1][0];
                const float4* gq = (const float4*)&h1s[wb][0];
                v2f a1 = v2f{dbA, 0.f}, a2 = v2f{dbB, 0.f};
#pragma unroll
                for (int q = 0; q < 5; ++q) {
                    const float4 hv = hq[q];
                    const float4 gv = gq[q];
                    a1 = __builtin_elementwise_fma(v2f{hv.x, hv.y}, wA[2 * q], a1);
                    a1 = __builtin_elementwise_fma(v2f{hv.z, hv.w}, wA[2 * q + 1], a1);
                    a2 = __builtin_elementwise_fma(v2f{gv.x, gv.y}, wB[2 * q], a2);
                    a2 = __builtin_elementwise_fma(v2f{gv.z, gv.w}, wB[2 * q + 1], a2);
                }
                const float xw1 = a1.x + a1.y;
                const float rec1 = a2.x + a2.y;

                const float sg1 = sigm(xw1 + rec1);
                const float rv1 = dpp_rshr1(sg1);
                const float zv1 = dpp_rshr1(rv1);
                const float hh1 = tanh_f(xw1 + rv1 * rec1);
                h1 = fmaf(zv1, h1 - hh1, hh1);
                if (home) h1s[wb][j] = h1;               // private staging
                LDSFENCE();
            }
        }
        __syncthreads();
    }

    // ---- dense (h1 @ Wd + bd) + softmax: L1 waves only ----
    if (isL1) {
        const int l = lane < LL ? lane : LL - 1;
        float acc = bd[l];
#pragma unroll
        for (int k = 0; k < HH; ++k)
            acc = fmaf(h1s[wb][k], Wd[k * LL + l], acc); // broadcast reads

        float m = acc;
#pragma unroll
        for (int i = 0; i < LL; ++i) m = fmaxf(m, bclane(acc, i));
        const float e = __expf(acc - m);
        float s = 0.f;
#pragma unroll
        for (int i = 0; i < LL; ++i) s += bclane(e, i);
        const float pr = e * fast_rcp(s);

        if (lane < LL) out[b * LL + lane] = pr;
    }
}

extern "C" void kernel_launch(void* const* d_in, const int* in_sizes, int n_in,
                              void* d_out, int out_size, void* d_ws, size_t ws_size,
                              hipStream_t stream) {
    const int*   x   = (const int*)  d_in[0];
    const float* W0  = (const float*)d_in[1];
    const float* U0  = (const float*)d_in[2];
    const float* b0i = (const float*)d_in[3];
    const float* b0r = (const float*)d_in[4];
    const float* W1  = (const float*)d_in[5];
    const float* U1  = (const float*)d_in[6];
    const float* b1i = (const float*)d_in[7];
    const float* b1r = (const float*)d_in[8];
    const float* Wd  = (const float*)d_in[9];
    const float* bd  = (const float*)d_in[10];
    // d_in[11] = drop_rate (identity), unused
    float* out = (float*)d_out;

    // 4 batches/block, 8 waves/block (4 L0 + 4 L1) -> 512 blocks of 512 thr
    // = 2 blocks/CU = 16 waves/CU = 4 waves/SIMD (one L0 + one L1 per block
    // per SIMD).
    dim3 grid(BB / 4), block(512);
    hipLaunchKernelGGL(gru2_kernel, grid, block, 0, stream,
                       x, W0, U0, b0i, b0r, W1, U1, b1i, b1r, Wd, bd, out);
}

// Round 17
// 133.095 us; speedup vs baseline: 1.6591x; 1.0576x over previous
//
#include <hip/hip_runtime.h>

// CharGRU2: 2-layer GRU (reset_after=true) + dense + softmax, fp32.
// B=2048, T=128, V=256, H=20, L=15.
//
// Round 17: PRODUCER-CONSUMER WAVE PAIRS, 2-wave blocks.
// R16's layer-split gave the predicted issue (775/SIMD-step) but lost to:
//   (a) per-step __syncthreads vmcnt(0) drain catching a W0 prefetch issued
//       ~100cyc earlier (L2 latency exposed every step),
//   (b) 8-wave barrier coupling 4 batches to the slowest,
//   (c) VGPR=52 < 80 pinned weights -> in-loop weight reloads.
// Fixes: block = ONE batch = 2 waves (L0 producer + L1 consumer, pairwise
// barrier); W0 prefetch issued at iteration TOP (~300cyc before the drain,
// W0 is L1/L2-resident so it completes); per-role weights (L0: U0 only = 40
// regs, L1: W1+U1 = 80) fit the 128-reg budget at waves_per_eu(4,4).
// 2048 blocks x 2 waves = 4096 waves = 4 waves/SIMD = 2 pairs/SIMD covering
// each other's stalls (R11 trunk has 2 waves/SIMD and a 420cyc/step gap).
//
// Per-batch layout unchanged (R11): lane 16r+3u+p owns gate column
// p*20+(5r+u) (p=0:z 1:r 2:h~); gate hops = 2 chained v_mov_dpp row_shr:1;
// h replicated via wave-uniform ds_read_b128 broadcasts.
// Schedule: iter i=0..128. L0 (i<128): rec0 = h0(t=i-1) [slot (i-1)&1] ->
// h0(t=i) -> slot i&1. L1 (i>=1): xw1 = h0(t=i-1)@W1, rec1 = h1(t=i-2)@U1
// (private h1s) -> h1(t=i-1). One pairwise barrier per iter.

#define BB 2048
#define TT 128
#define HH 20
#define LL 15
#define H3 60

typedef float v2f __attribute__((ext_vector_type(2)));

__device__ __forceinline__ float bclane(float v, int k) {
    return __int_as_float(__builtin_amdgcn_readlane(__float_as_int(v), k));
}
__device__ __forceinline__ float dpp_rshr1(float v) {
    return __int_as_float(__builtin_amdgcn_update_dpp(
        0, __float_as_int(v), 0x111, 0xF, 0xF, true));
}
__device__ __forceinline__ float fast_rcp(float x) { return __builtin_amdgcn_rcpf(x); }
__device__ __forceinline__ float sigm(float x) { return fast_rcp(1.f + __expf(-x)); }
__device__ __forceinline__ float tanh_f(float x) { return 1.f - 2.f * fast_rcp(1.f + __expf(2.f * x)); }
#define PIN(v) asm volatile("" : "+v"(v))
#define LDSFENCE() asm volatile("" ::: "memory")

extern "C" __global__ __launch_bounds__(128)
__attribute__((amdgpu_waves_per_eu(4, 4)))
void gru2_kernel(const int* __restrict__ x, const float* __restrict__ W0,
                 const float* __restrict__ U0, const float* __restrict__ b0i,
                 const float* __restrict__ b0r, const float* __restrict__ W1,
                 const float* __restrict__ U1, const float* __restrict__ b1i,
                 const float* __restrict__ b1r, const float* __restrict__ Wd,
                 const float* __restrict__ bd, float* __restrict__ out)
{
    const int lane = threadIdx.x & 63;
    const bool isL1 = (threadIdx.x >= 64);               // wave role
    const int b = blockIdx.x;                            // one batch per block

    const int pos = lane & 15;
    const int pc  = (pos < 15) ? pos : 14;               // lane 16r+15 dups
    const int u   = pc / 3;
    const int p3  = pc % 3;                              // 0:z 1:r 2:h~
    const int j   = (lane >> 4) * 5 + u;                 // unit 0..19
    const bool home = (pos < 15) && (p3 == 2);
    const int col = p3 * 20 + j;

    // h0 hand-off (double-buffered) + L1-private h1 staging
    __shared__ __align__(16) float h0x[2][24];
    __shared__ __align__(16) float h1s[24];
    if (!isL1 && home) { h0x[0][j] = 0.f; h0x[1][j] = 0.f; }
    if (isL1 && home)  { h1s[j] = 0.f; }
    __syncthreads();

    // ---- role-specific weights (k-pair packed), pinned ----
    // L0: wA = U0 (rec0). L1: wA = W1 (xw1), wB = U1 (rec1).
    const float* MA = isL1 ? W1 : U0;
    v2f wA[10], wB[10];
#pragma unroll
    for (int q = 0; q < 10; ++q) {
        const int k0 = (2 * q) * H3, k1 = (2 * q + 1) * H3;
        wA[q] = v2f{MA[k0 + col], MA[k1 + col]};
    }
#pragma unroll
    for (int q = 0; q < 10; ++q) PIN(wA[q]);
    if (isL1) {
#pragma unroll
        for (int q = 0; q < 10; ++q) {
            const int k0 = (2 * q) * H3, k1 = (2 * q + 1) * H3;
            wB[q] = v2f{U1[k0 + col], U1[k1 + col]};
        }
#pragma unroll
        for (int q = 0; q < 10; ++q) PIN(wB[q]);
    }
    const float dbA = isL1 ? b1i[col] : b0r[col];
    const float dbB = isL1 ? b1r[col] : 0.f;
    const float bi0c = b0i[col];

    // ---- L0-only: tokens + W0 software pipeline ----
    const int* xrow = x + b * TT;
    int tokA = 0, tokB = 0, tokn2 = 0;
    float xw_cur = 0.f, xw_nxt = 0.f;
    if (!isL1) {
        tokA = xrow[lane];
        tokB = xrow[64 + lane];
        tokn2 = __builtin_amdgcn_readlane(tokA, 2);
        xw_cur = W0[__builtin_amdgcn_readlane(tokA, 0) * H3 + col] + bi0c;
        xw_nxt = W0[__builtin_amdgcn_readlane(tokA, 1) * H3 + col];
    }

    float h0 = 0.f, h1 = 0.f;

    for (int i = 0; i <= TT; ++i) {
        if (!isL1) {
            if (i < TT) {
                // prefetch at iteration TOP: completes long before the
                // barrier's vmcnt(0) drain (W0 is L1/L2-resident)
                const int t3 = (i + 3 < TT) ? (i + 3) : (TT - 1);
                const float pf = W0[tokn2 * H3 + col];
                const int tokn3 =
                    __builtin_amdgcn_readlane(t3 < 64 ? tokA : tokB, t3 & 63);

                // rec0 = h0(t=i-1) @ U0 + br0  [slot (i-1)&1]
                const float4* hq = (const float4*)&h0x[(i + 1) & 1][0];
                v2f a0 = v2f{dbA, 0.f}, a0b = v2f{0.f, 0.f};
#pragma unroll
                for (int q = 0; q < 5; ++q) {
                    const float4 hv = hq[q];
                    a0  = __builtin_elementwise_fma(v2f{hv.x, hv.y}, wA[2 * q], a0);
                    a0b = __builtin_elementwise_fma(v2f{hv.z, hv.w}, wA[2 * q + 1], a0b);
                }
                const float rec0 = (a0.x + a0.y) + (a0b.x + a0b.y);

                const float sg0 = sigm(xw_cur + rec0);
                const float rv0 = dpp_rshr1(sg0);
                const float zv0 = dpp_rshr1(rv0);
                const float hh0 = tanh_f(xw_cur + rv0 * rec0);
                h0 = fmaf(zv0, h0 - hh0, hh0);
                if (home) h0x[i & 1][j] = h0;
                LDSFENCE();

                xw_cur = xw_nxt + bi0c; xw_nxt = pf; tokn2 = tokn3;
            }
        } else {
            if (i >= 1) {
                // xw1 = h0(t=i-1) @ W1 + bi1 ; rec1 = h1(t=i-2) @ U1 + br1
                const float4* hq = (const float4*)&h0x[(i + 1) & 1][0];
                const float4* gq = (const float4*)&h1s[0];
                v2f a1 = v2f{dbA, 0.f}, a1b = v2f{0.f, 0.f};
                v2f a2 = v2f{dbB, 0.f}, a2b = v2f{0.f, 0.f};
#pragma unroll
                for (int q = 0; q < 5; ++q) {
                    const float4 hv = hq[q];
                    const float4 gv = gq[q];
                    a1  = __builtin_elementwise_fma(v2f{hv.x, hv.y}, wA[2 * q], a1);
                    a1b = __builtin_elementwise_fma(v2f{hv.z, hv.w}, wA[2 * q + 1], a1b);
                    a2  = __builtin_elementwise_fma(v2f{gv.x, gv.y}, wB[2 * q], a2);
                    a2b = __builtin_elementwise_fma(v2f{gv.z, gv.w}, wB[2 * q + 1], a2b);
                }
                const float xw1  = (a1.x + a1.y) + (a1b.x + a1b.y);
                const float rec1 = (a2.x + a2.y) + (a2b.x + a2b.y);

                const float sg1 = sigm(xw1 + rec1);
                const float rv1 = dpp_rshr1(sg1);
                const float zv1 = dpp_rshr1(rv1);
                const float hh1 = tanh_f(xw1 + rv1 * rec1);
                h1 = fmaf(zv1, h1 - hh1, hh1);
                if (home) h1s[j] = h1;
                LDSFENCE();
            }
        }
        __syncthreads();                                 // pairwise (2 waves)
    }

    // ---- dense (h1 @ Wd + bd) + softmax: L1 wave only ----
    if (isL1) {
        const int l = lane < LL ? lane : LL - 1;
        float acc = bd[l];
#pragma unroll
        for (int k = 0; k < HH; ++k)
            acc = fmaf(h1s[k], Wd[k * LL + l], acc);     // broadcast reads

        float m = acc;
#pragma unroll
        for (int i = 0; i < LL; ++i) m = fmaxf(m, bclane(acc, i));
        const float e = __expf(acc - m);
        float s = 0.f;
#pragma unroll
        for (int i = 0; i < LL; ++i) s += bclane(e, i);
        const float pr = e * fast_rcp(s);

        if (lane < LL) out[b * LL + lane] = pr;
    }
}

extern "C" void kernel_launch(void* const* d_in, const int* in_sizes, int n_in,
                              void* d_out, int out_size, void* d_ws, size_t ws_size,
                              hipStream_t stream) {
    const int*   x   = (const int*)  d_in[0];
    const float* W0  = (const float*)d_in[1];
    const float* U0  = (const float*)d_in[2];
    const float* b0i = (const float*)d_in[3];
    const float* b0r = (const float*)d_in[4];
    const float* W1  = (const float*)d_in[5];
    const float* U1  = (const float*)d_in[6];
    const float* b1i = (const float*)d_in[7];
    const float* b1r = (const float*)d_in[8];
    const float* Wd  = (const float*)d_in[9];
    const float* bd  = (const float*)d_in[10];
    // d_in[11] = drop_rate (identity), unused
    float* out = (float*)d_out;

    // one batch per 2-wave block: 2048 blocks x 128 threads
    // = 4096 waves = 8 blocks/CU = 4 waves/SIMD (2 producer-consumer pairs).
    dim3 grid(BB), block(128);
    hipLaunchKernelGGL(gru2_kernel, grid, block, 0, stream,
                       x, W0, U0, b0i, b0r, W1, U1, b1i, b1r, Wd, bd, out);
}